// Round 20
// baseline (281.237 us; speedup 1.0000x reference)
//
#include <hip/hip_runtime.h>

// ---------- types ----------
typedef short short8 __attribute__((ext_vector_type(8)));     // 8 bf16 bit-patterns (4 VGPRs) - MFMA A/B frag
typedef float f32x4 __attribute__((ext_vector_type(4)));      // MFMA C/D frag
typedef unsigned short u16x8 __attribute__((ext_vector_type(8)));
typedef unsigned short u16x4 __attribute__((ext_vector_type(4)));

#define B_DIM 4096
#define IN_DIM 512
#define H_DIM 1024
#define KCAT 1536   // IN_DIM + H_DIM

__device__ __forceinline__ float bs2f(unsigned short s) {
    return __uint_as_float(((unsigned int)s) << 16);
}
__device__ __forceinline__ unsigned short f2bs(float f) {
    unsigned int u = __float_as_uint(f);
    u += 0x7fff + ((u >> 16) & 1);   // RNE
    return (unsigned short)(u >> 16);
}
__device__ __forceinline__ float sigm(float x) { return 1.0f / (1.0f + __expf(-x)); }
__device__ __forceinline__ float ftanh(float x) { return 1.0f - 2.0f / (__expf(2.0f * x) + 1.0f); }

// gate-interleave permutation: orig gate row r (g=r>>10, j=r&1023) -> n' = (j>>4)*64 + g*16 + (j&15)
__device__ __forceinline__ int gperm(int r) {
    int g = r >> 10, j = r & 1023;
    return ((j >> 4) << 6) + (g << 4) + (j & 15);
}

// ---------- fused f32 -> bf16 pack ----------
#define T0 262144    // x    [4096,512]  -> xb flat
#define T1 786432    // h0   [4096,1024] -> hb0 flat
#define T2 1048576   // wih  [4096,512]  -> wcat interleaved rows, col off 0
#define T3 1572864   // whh  [4096,1024] -> wcat interleaved rows, col off 512
#define T4 1703936   // w1   [1024,1024] -> w116 flat
#define T5 1835008   // w2   [1024,1024] -> w216 flat
__device__ __forceinline__ u16x8 cvt8(const float* __restrict__ in, long i) {
    float4 a = *(const float4*)(in + i);
    float4 b = *(const float4*)(in + i + 4);
    u16x8 o;
    o[0] = f2bs(a.x); o[1] = f2bs(a.y); o[2] = f2bs(a.z); o[3] = f2bs(a.w);
    o[4] = f2bs(b.x); o[5] = f2bs(b.y); o[6] = f2bs(b.z); o[7] = f2bs(b.w);
    return o;
}
__global__ __launch_bounds__(256) void pack_all(const float* __restrict__ x,
                                                const float* __restrict__ h0,
                                                const float* __restrict__ wih,
                                                const float* __restrict__ whh,
                                                const float* __restrict__ w1,
                                                const float* __restrict__ w2,
                                                unsigned short* __restrict__ xb,
                                                unsigned short* __restrict__ hb0,
                                                unsigned short* __restrict__ wcat,
                                                unsigned short* __restrict__ w116,
                                                unsigned short* __restrict__ w216) {
    long g = (long)blockIdx.x * 256 + threadIdx.x;
    if (g < T0) {
        long i = g * 8;
        *(u16x8*)(xb + i) = cvt8(x, i);
    } else if (g < T1) {
        long i = (g - T0) * 8;
        *(u16x8*)(hb0 + i) = cvt8(h0, i);
    } else if (g < T2) {
        long i = (g - T1) * 8;
        int r = (int)(i / IN_DIM), c = (int)(i % IN_DIM);
        *(u16x8*)(wcat + (size_t)gperm(r) * KCAT + c) = cvt8(wih, i);
    } else if (g < T3) {
        long i = (g - T2) * 8;
        int r = (int)(i / H_DIM), c = (int)(i % H_DIM);
        *(u16x8*)(wcat + (size_t)gperm(r) * KCAT + IN_DIM + c) = cvt8(whh, i);
    } else if (g < T4) {
        long i = (g - T3) * 8;
        *(u16x8*)(w116 + i) = cvt8(w1, i);
    } else if (g < T5) {
        long i = (g - T4) * 8;
        *(u16x8*)(w216 + i) = cvt8(w2, i);
    }
}

// ---------- W2 transpose pack ----------
__global__ __launch_bounds__(256) void transp_w2(const float* __restrict__ w2,
                                                 unsigned short* __restrict__ w2t) {
    int tid = blockIdx.x * 256 + threadIdx.x;
    int t = tid & 1023;
    int jb = tid >> 10;
    float4 a = *(const float4*)(w2 + (size_t)t * H_DIM + jb * 8);
    float4 b = *(const float4*)(w2 + (size_t)t * H_DIM + jb * 8 + 4);
    float v[8] = {a.x, a.y, a.z, a.w, b.x, b.y, b.z, b.w};
    #pragma unroll
    for (int q = 0; q < 8; ++q)
        w2t[(size_t)(jb * 8 + q) * H_DIM + t] = f2bs(v[q]);
}

// ---------- bc[n] = sum_k b2[k] * W1[n,k] ----------
__global__ __launch_bounds__(256) void bck(const float* __restrict__ b2,
                                           const float* __restrict__ w1,
                                           float* __restrict__ bc) {
    __shared__ float ws[4];
    int n = blockIdx.x;
    int t = threadIdx.x;
    float4 bv = *(const float4*)(b2 + t * 4);
    float4 wv = *(const float4*)(w1 + (size_t)n * H_DIM + t * 4);
    float p = bv.x * wv.x + bv.y * wv.y + bv.z * wv.z + bv.w * wv.w;
    #pragma unroll
    for (int off = 32; off > 0; off >>= 1) p += __shfl_down(p, off);
    if ((t & 63) == 0) ws[t >> 6] = p;
    __syncthreads();
    if (t == 0) bc[n] = ws[0] + ws[1] + ws[2] + ws[3];
}

// ---------- bias sum (gate-permuted) + dt ----------
__global__ __launch_bounds__(256) void prep_small(const float* __restrict__ bih,
                                                  const float* __restrict__ bhh,
                                                  const float* __restrict__ ts,
                                                  float* __restrict__ bsum,
                                                  float* __restrict__ dtv,
                                                  int n4h, int nb) {
    int i = blockIdx.x * blockDim.x + threadIdx.x;
    if (i < n4h) bsum[gperm(i)] = bih[i] + bhh[i];
    if (i < nb)  dtv[i] = ts[2 * i + 1] - ts[2 * i];
}

// ===== 8-wave gates kernel: 128x256 tile, 512 blocks, 2-BUFFER (48 KiB -> 3 blocks/CU) =====
// r20: switched 3-buf -> 2-buf using the r13-proven pattern: per K-tile
// {vmcnt(0); barrier; read frags(buf kt&1); stage(kt+1 -> buf^1); MFMA}.
// WAR proof: stage(kt+1) writes buf^1 holding kt-1 data; every wave's kt-1 frag reads
// completed before its MFMA(kt-1) (lgkm data-dep) which precedes barrier(kt).
// vmcnt(0) costs ~0: certified loads were issued a full iteration (~1100cy) earlier.
// MODE 0 (GX): A = xb, K=512; Gx4 u16x4 store.  MODE 1 (CELL): A = hb, K=1024; fused LSTM.
template <int MODE>
__global__ __launch_bounds__(512) void gemm8(
    const unsigned short* __restrict__ A,    // xb (MODE0) or hb (MODE1)
    const unsigned short* __restrict__ W,    // wcat (+IN_DIM for MODE1), stride KCAT
    const float* __restrict__ bias,          // MODE0: bsum (gate-permuted)
    unsigned short* __restrict__ gx,         // [B][H][4] u16 gate-last
    unsigned short* __restrict__ h_out,      // MODE1: [B,H] bf16
    float* __restrict__ c_out,               // MODE1: [B,H] f32
    const float* __restrict__ c_in) {        // MODE1: [B,H] f32
    constexpr int KA = (MODE == 0) ? IN_DIM : H_DIM;
    constexpr int NT = KA / 32;              // 16 or 32
    __shared__ unsigned short lA[2][128 * 32];   // 16 KiB
    __shared__ unsigned short lB[2][256 * 32];   // 32 KiB
    const int t = threadIdx.x;
    const int lane = t & 63;
    const int wave = t >> 6;
    const int wm = (wave >> 2) * 64;    // 0 or 64
    const int wn = (wave & 3) * 64;     // 0,64,128,192
    const int fr = lane & 15;
    const int kb = lane >> 4;
    const int tile_m = blockIdx.y * 128;
    const int tile_n = blockIdx.x * 256;

    f32x4 acc[4][4];
    #pragma unroll
    for (int i = 0; i < 4; ++i)
        #pragma unroll
        for (int j = 0; j < 4; ++j)
            acc[i][j] = (f32x4){0.f, 0.f, 0.f, 0.f};

    // loop-invariant LDS fragment byte offsets (swizzle depends only on row)
    int aoff[4], boff[4];
    #pragma unroll
    for (int i = 0; i < 4; ++i) {
        int arow = wm + i * 16 + fr;
        aoff[i] = arow * 32 + (kb ^ ((arow >> 1) & 3)) * 8;
    }
    #pragma unroll
    for (int j = 0; j < 4; ++j) {
        int brow = wn + j * 16 + fr;
        boff[j] = brow * 32 + (kb ^ ((brow >> 1) & 3)) * 8;
    }

    auto stageA = [&](int kt) {
        const int buf = kt & 1;
        int row = t >> 2;
        int g = t & 3;
        int gs = g ^ ((row >> 1) & 3);
        int kk = kt * 32 + gs * 8;
        __builtin_amdgcn_global_load_lds(
            (__attribute__((address_space(1))) void*)(A + (size_t)(tile_m + row) * KA + kk),
            (__attribute__((address_space(3))) void*)(&lA[buf][row * 32 + g * 8]), 16, 0, 0);
    };
    auto stageB = [&](int kt) {
        const int buf = kt & 1;
        #pragma unroll
        for (int j = 0; j < 2; ++j) {
            int idx = j * 512 + t;
            int row = idx >> 2;
            int g = idx & 3;
            int gs = g ^ ((row >> 1) & 3);
            int kk = kt * 32 + gs * 8;
            __builtin_amdgcn_global_load_lds(
                (__attribute__((address_space(1))) void*)(W + (size_t)(tile_n + row) * KCAT + kk),
                (__attribute__((address_space(3))) void*)(&lB[buf][row * 32 + g * 8]), 16, 0, 0);
        }
    };

    stageA(0); stageB(0);

    for (int kt = 0; kt < NT; ++kt) {
        const int buf = kt & 1;
        asm volatile("s_waitcnt vmcnt(0)" ::: "memory");
        __builtin_amdgcn_s_barrier();
        asm volatile("" ::: "memory");     // nothing crosses above the barrier
        short8 bfr[4], af[4];
        #pragma unroll
        for (int j = 0; j < 4; ++j) bfr[j] = *(const short8*)&lB[buf][boff[j]];
        #pragma unroll
        for (int i = 0; i < 4; ++i) af[i] = *(const short8*)&lA[buf][aoff[i]];
        if (kt + 1 < NT) { stageA(kt + 1); stageB(kt + 1); }   // issue next-tile loads
        __builtin_amdgcn_s_setprio(1);
        #pragma unroll
        for (int i = 0; i < 4; ++i)
            #pragma unroll
            for (int j = 0; j < 4; ++j)
                acc[i][j] = __builtin_amdgcn_mfma_f32_16x16x32_bf16(af[i], bfr[j], acc[i][j], 0, 0, 0);
        __builtin_amdgcn_s_setprio(0);
        asm volatile("" ::: "memory");
    }

    const int jbase = ((tile_n + wn) >> 6) << 4;
    if (MODE == 0) {
        float bv[4];
        #pragma unroll
        for (int g = 0; g < 4; ++g) bv[g] = bias[tile_n + wn + g * 16 + fr];
        #pragma unroll
        for (int i = 0; i < 4; ++i) {
            #pragma unroll
            for (int r = 0; r < 4; ++r) {
                const int m = tile_m + wm + i * 16 + kb * 4 + r;
                const int j = jbase + fr;
                u16x4 o;
                #pragma unroll
                for (int g = 0; g < 4; ++g) o[g] = f2bs(acc[i][g][r] + bv[g]);
                *(u16x4*)(gx + ((size_t)m * H_DIM + j) * 4) = o;
            }
        }
    } else {
        #pragma unroll
        for (int i = 0; i < 4; ++i) {
            #pragma unroll
            for (int r = 0; r < 4; ++r) {
                const int m = tile_m + wm + i * 16 + kb * 4 + r;
                const int j = jbase + fr;
                u16x4 gv = *(const u16x4*)(gx + ((size_t)m * H_DIM + j) * 4);
                float ig = sigm(acc[i][0][r] + bs2f(gv[0]));
                float fg = sigm(acc[i][1][r] + bs2f(gv[1]));
                float gg = ftanh(acc[i][2][r] + bs2f(gv[2]));
                float og = sigm(acc[i][3][r] + bs2f(gv[3]));
                float cin = c_in[(size_t)m * H_DIM + j];
                float cn = fg * cin + ig * gg;
                float hn = og * ftanh(cn);
                h_out[(size_t)m * H_DIM + j] = f2bs(hn);
                c_out[(size_t)m * H_DIM + j] = cn;
            }
        }
    }
}

// ---------- RK4 GEMM (r13 structure): 64x64 tile, BK=64, 2-buffer, 1 barrier/K-step ----------
// Composed z-space RK4 with bf16 side-band state.
// EPI: 0 = bf16(v [+bias]) -> outb                          (Wc build)
//      5 = z1-GEMM: z1b=bf16(v+b1); outb=bf16(tanh(v+b1))   (u1, tanh from f32 z1)
//      6 = g-GEMM: v+=bc; z=z1b+alpha*dt*v; u=tanh(z);
//          first: Ub=bf16(u1b + cw*u); mid: Ub=bf16(Ub+cw*u); last: outb=bf16(Ub+cw*u)
//          non-last: outb=bf16(u)
//      7 = final: ht = h + dt*(v/6 + b2[n]) -> outf
template <int EPI>
__global__ __launch_bounds__(256) void gemm2(
    const unsigned short* __restrict__ A1,
    const unsigned short* __restrict__ W,
    const int M, const int N, const int K,
    const float* __restrict__ bias,
    unsigned short* __restrict__ outb,
    float* __restrict__ outf,
    const unsigned short* __restrict__ z1b,   // bf16 z1
    unsigned short* __restrict__ Ub,          // bf16 U accumulator
    const unsigned short* __restrict__ u1b,   // bf16 u1 (EPI6 first)
    const unsigned short* __restrict__ hmat,
    const float* __restrict__ dtv,
    const float alpha, const float cw, const int first, const int last) {
    constexpr int BM = 64, BN = 64, BK = 64;
    constexpr int MR = 2, NR = 2;
    __shared__ unsigned short lA[2][BM * BK];
    __shared__ unsigned short lB[2][BN * BK];
    const int t = threadIdx.x;
    const int lane = t & 63;
    const int wave = t >> 6;
    const int wm = (wave >> 1) * 32;
    const int wn = (wave & 1) * 32;
    const int fr = lane & 15;
    const int kb = lane >> 4;
    const int tile_m = blockIdx.y * BM;
    const int tile_n = blockIdx.x * BN;

    f32x4 acc[MR][NR];
    #pragma unroll
    for (int i = 0; i < MR; ++i)
        #pragma unroll
        for (int j = 0; j < NR; ++j)
            acc[i][j] = (f32x4){0.f, 0.f, 0.f, 0.f};

    const unsigned short* aptr1 = A1 + (size_t)tile_m * K;
    const unsigned short* wptr  = W + (size_t)tile_n * K;

    auto stage = [&](int kt) {
        const int buf = kt & 1;
        const int k0 = kt * BK;
        #pragma unroll
        for (int j = 0; j < 2; ++j) {
            int idx = j * 256 + t;
            int row = idx >> 3;
            int g = idx & 7;
            int col = (g ^ (row & 7)) * 8;
            __builtin_amdgcn_global_load_lds(
                (__attribute__((address_space(1))) void*)(aptr1 + (size_t)row * K + k0 + col),
                (__attribute__((address_space(3))) void*)(&lA[buf][row * BK + g * 8]), 16, 0, 0);
        }
        #pragma unroll
        for (int j = 0; j < 2; ++j) {
            int idx = j * 256 + t;
            int row = idx >> 3;
            int g = idx & 7;
            int col = (g ^ (row & 7)) * 8;
            __builtin_amdgcn_global_load_lds(
                (__attribute__((address_space(1))) void*)(wptr + (size_t)row * K + k0 + col),
                (__attribute__((address_space(3))) void*)(&lB[buf][row * BK + g * 8]), 16, 0, 0);
        }
    };

    const int NT = K / BK;   // 16
    stage(0);
    for (int kt = 0; kt < NT; ++kt) {
        const int buf = kt & 1;
        asm volatile("s_waitcnt vmcnt(0)" ::: "memory");
        __builtin_amdgcn_s_barrier();
        asm volatile("" ::: "memory");     // nothing crosses above the barrier
        short8 af[2][MR], bfr[2][NR];
        #pragma unroll
        for (int h = 0; h < 2; ++h) {
            #pragma unroll
            for (int i = 0; i < MR; ++i) {
                int arow = wm + i * 16 + fr;
                int gidx = h * 4 + kb;
                af[h][i] = *(const short8*)&lA[buf][arow * BK + (gidx ^ (arow & 7)) * 8];
            }
            #pragma unroll
            for (int j = 0; j < NR; ++j) {
                int brow = wn + j * 16 + fr;
                int gidx = h * 4 + kb;
                bfr[h][j] = *(const short8*)&lB[buf][brow * BK + (gidx ^ (brow & 7)) * 8];
            }
        }
        if (kt + 1 < NT) stage(kt + 1);    // issue next-tile loads; overlap MFMA
        #pragma unroll
        for (int h = 0; h < 2; ++h)
            #pragma unroll
            for (int i = 0; i < MR; ++i)
                #pragma unroll
                for (int j = 0; j < NR; ++j)
                    acc[i][j] = __builtin_amdgcn_mfma_f32_16x16x32_bf16(af[h][i], bfr[h][j], acc[i][j], 0, 0, 0);
        asm volatile("" ::: "memory");
    }

    #pragma unroll
    for (int i = 0; i < MR; ++i) {
        #pragma unroll
        for (int r = 0; r < 4; ++r) {
            const int m = tile_m + wm + i * 16 + kb * 4 + r;
            float dt = 0.f;
            if (EPI >= 6) dt = dtv[m];
            #pragma unroll
            for (int j = 0; j < NR; ++j) {
                const int n = tile_n + wn + j * 16 + fr;
                const size_t off = (size_t)m * N + n;
                float v = acc[i][j][r];
                if (EPI == 0) {
                    if (bias) v += bias[n];
                    outb[off] = f2bs(v);
                } else if (EPI == 5) {
                    v += bias[n];
                    Ub[off] = f2bs(v);             // z1 (bf16) -- Ub arg doubles as z1b out
                    outb[off] = f2bs(ftanh(v));    // u1 (tanh from f32 z1)
                } else if (EPI == 6) {
                    v += bias[n];                  // + bc
                    float z1v = bs2f(z1b[off]);
                    float z = z1v + alpha * dt * v;
                    float u = ftanh(z);
                    if (first) {
                        Ub[off] = f2bs(bs2f(u1b[off]) + cw * u);
                        outb[off] = f2bs(u);
                    } else if (last) {
                        outb[off] = f2bs(bs2f(Ub[off]) + cw * u);
                    } else {
                        Ub[off] = f2bs(bs2f(Ub[off]) + cw * u);
                        outb[off] = f2bs(u);
                    }
                } else { // EPI == 7: final
                    float hv = bs2f(hmat[off]);
                    outf[off] = hv + dt * (v * (1.0f / 6.0f) + bias[n]);
                }
            }
        }
    }
}

// ---------- launch ----------
extern "C" void kernel_launch(void* const* d_in, const int* in_sizes, int n_in,
                              void* d_out, int out_size, void* d_ws, size_t ws_size,
                              hipStream_t stream) {
    int IX = 0, IH0 = 1, IC0 = 2, ITS = 3, IWIH = 4, IWHH = 5, IBIH = 6, IBHH = 7,
        IW1 = 8, IB1 = 9, IW2 = 10, IB2 = 11;
    const bool sorted_ok = n_in >= 12 &&
        in_sizes[0] == 1024 && in_sizes[1] == 1024 && in_sizes[2] == 4096 &&
        in_sizes[3] == 4096 && in_sizes[4] == 4194304 && in_sizes[5] == 4194304 &&
        in_sizes[6] == 2097152 && in_sizes[7] == 8192 && in_sizes[8] == 1048576 &&
        in_sizes[9] == 1048576 && in_sizes[10] == 4194304 && in_sizes[11] == 2097152;
    if (sorted_ok) { // b1,b2,b_hh,b_ih,c0,h0,inputs,ts,w1,w2,w_hh,w_ih
        IB1 = 0; IB2 = 1; IBHH = 2; IBIH = 3; IC0 = 4; IH0 = 5;
        IX = 6; ITS = 7; IW1 = 8; IW2 = 9; IWHH = 10; IWIH = 11;
    }
    const float* x_f   = (const float*)d_in[IX];
    const float* h0_f  = (const float*)d_in[IH0];
    const float* c0_f  = (const float*)d_in[IC0];
    const float* ts_f  = (const float*)d_in[ITS];
    const float* wih_f = (const float*)d_in[IWIH];
    const float* whh_f = (const float*)d_in[IWHH];
    const float* bih_f = (const float*)d_in[IBIH];
    const float* bhh_f = (const float*)d_in[IBHH];
    const float* w1_f  = (const float*)d_in[IW1];
    const float* b1_f  = (const float*)d_in[IB1];
    const float* w2_f  = (const float*)d_in[IW2];
    const float* b2_f  = (const float*)d_in[IB2];

    constexpr size_t SZ_BIN  = (size_t)B_DIM * IN_DIM;       // 2M
    constexpr size_t SZ_BH   = (size_t)B_DIM * H_DIM;        // 4M
    constexpr size_t SZ_HH   = (size_t)H_DIM * H_DIM;        // 1M
    constexpr size_t SZ_WCAT = (size_t)4 * H_DIM * KCAT;     // 6M

    // workspace: f32 regions first, then bf16
    float* bsum = (float*)d_ws;                    // 4H (gate-permuted)
    float* dtv  = bsum + 4 * H_DIM;                // B
    float* bc   = dtv + B_DIM;                     // H
    float* S    = bc + H_DIM;                      // [B,H] f32: c1 (cell1 -> cell2)
    unsigned short* z1b16 = (unsigned short*)(S + SZ_BH);    // [B,H] bf16 z1
    unsigned short* Ub16  = z1b16 + SZ_BH;         // [B,H] bf16 U accumulator
    unsigned short* wcat = Ub16 + SZ_BH;           // [4H,KCAT]
    unsigned short* w116 = wcat + SZ_WCAT;         // [H,H]
    unsigned short* w216 = w116 + SZ_HH;           // [H,H]
    unsigned short* w2t  = w216 + SZ_HH;           // [H,H] W2^T
    unsigned short* wc16 = w2t + SZ_HH;            // [H,H] Wc = W1@W2
    unsigned short* xb   = wc16 + SZ_HH;           // [B,512]
    unsigned short* hb0  = xb + SZ_BIN;            // [B,H]
    unsigned short* hb1  = hb0 + SZ_BH;            // [B,H]
    unsigned short* hb2  = hb1 + SZ_BH;            // [B,H]
    unsigned short* ubuf = hb2 + SZ_BH;            // [B,H]
    unsigned short* ybuf = ubuf + SZ_BH;           // [B,H]
    unsigned short* Gx   = ybuf + SZ_BH;           // [B][H][4] u16 gate-last (32 MB)

    float* out_ht = (float*)d_out;                 // [B,H] f32
    float* out_c  = out_ht + SZ_BH;                // [B,H] f32

    const int TB = 256;
    pack_all<<<T5 / TB, TB, 0, stream>>>(x_f, h0_f, wih_f, whh_f, w1_f, w2_f,
                                         xb, hb0, wcat, w116, w216);
    transp_w2<<<(H_DIM * H_DIM / 8) / TB, TB, 0, stream>>>(w2_f, w2t);
    prep_small<<<(4 * H_DIM) / TB, TB, 0, stream>>>(bih_f, bhh_f, ts_f, bsum, dtv, 4 * H_DIM, B_DIM);
    bck<<<H_DIM, TB, 0, stream>>>(b2_f, w1_f, bc);

    dim3 g8(4 * H_DIM / 256, B_DIM / 128);     // (16,32) = 512 blocks, 512 thr, 3/CU
    dim3 gSm(H_DIM / 64, B_DIM / 64);          // (16,64) = 1024 blocks
    dim3 gWc(H_DIM / 64, H_DIM / 64);          // (16,16) = 256 blocks

    // Wc = W1 @ W2
    gemm2<0><<<gWc, TB, 0, stream>>>(w116, w2t, H_DIM, H_DIM, H_DIM, nullptr,
                                     wc16, nullptr, nullptr, nullptr, nullptr, nullptr, nullptr,
                                     0.f, 0.f, 0, 0);

    // Gx = x @ Wih^T + bsum  (K=512, computed ONCE for both cells; gate-last u16x4)
    gemm8<0><<<g8, 512, 0, stream>>>(xb, wcat, bsum, Gx, nullptr, nullptr, nullptr);

    // cell 1 (K=1024 h-part + Gx in epilogue): h0 -> h1 (hb1), c1 -> S
    gemm8<1><<<g8, 512, 0, stream>>>(hb0, wcat + IN_DIM, nullptr, Gx, hb1, S, c0_f);
    // cell 2: h1 -> h2 (hb2), c2 -> out_c
    gemm8<1><<<g8, 512, 0, stream>>>(hb1, wcat + IN_DIM, nullptr, Gx, hb2, out_c, S);

    // Composed RK4 in z-space (bf16 z1/U side-band):
    gemm2<5><<<gSm, TB, 0, stream>>>(hb2, w116, B_DIM, H_DIM, H_DIM, b1_f,
                                     ubuf, nullptr, nullptr, z1b16, nullptr, nullptr, nullptr,
                                     0.f, 0.f, 0, 0);
    gemm2<6><<<gSm, TB, 0, stream>>>(ubuf, wc16, B_DIM, H_DIM, H_DIM, bc,
                                     ybuf, nullptr, z1b16, Ub16, ubuf, nullptr, dtv,
                                     0.5f, 2.0f, 1, 0);
    gemm2<6><<<gSm, TB, 0, stream>>>(ybuf, wc16, B_DIM, H_DIM, H_DIM, bc,
                                     ubuf, nullptr, z1b16, Ub16, nullptr, nullptr, dtv,
                                     0.5f, 2.0f, 0, 0);
    gemm2<6><<<gSm, TB, 0, stream>>>(ubuf, wc16, B_DIM, H_DIM, H_DIM, bc,
                                     hb1, nullptr, z1b16, Ub16, nullptr, nullptr, dtv,
                                     1.0f, 1.0f, 0, 1);
    gemm2<7><<<gSm, TB, 0, stream>>>(hb1, w216, B_DIM, H_DIM, H_DIM, b2_f,
                                     nullptr, out_ht, nullptr, nullptr, nullptr, hb2, dtv,
                                     0.f, 0.f, 0, 0);
}

// Round 21
// 274.552 us; speedup vs baseline: 1.0243x; 1.0243x over previous
//
#include <hip/hip_runtime.h>

// ---------- types ----------
typedef short short8 __attribute__((ext_vector_type(8)));     // 8 bf16 bit-patterns (4 VGPRs) - MFMA A/B frag
typedef float f32x4 __attribute__((ext_vector_type(4)));      // MFMA C/D frag
typedef unsigned short u16x8 __attribute__((ext_vector_type(8)));
typedef unsigned short u16x4 __attribute__((ext_vector_type(4)));

#define B_DIM 4096
#define IN_DIM 512
#define H_DIM 1024
#define KCAT 1536   // IN_DIM + H_DIM

__device__ __forceinline__ float bs2f(unsigned short s) {
    return __uint_as_float(((unsigned int)s) << 16);
}
__device__ __forceinline__ unsigned short f2bs(float f) {
    unsigned int u = __float_as_uint(f);
    u += 0x7fff + ((u >> 16) & 1);   // RNE
    return (unsigned short)(u >> 16);
}
__device__ __forceinline__ float sigm(float x) { return 1.0f / (1.0f + __expf(-x)); }
__device__ __forceinline__ float ftanh(float x) { return 1.0f - 2.0f / (__expf(2.0f * x) + 1.0f); }

// gate-interleave permutation: orig gate row r (g=r>>10, j=r&1023) -> n' = (j>>4)*64 + g*16 + (j&15)
__device__ __forceinline__ int gperm(int r) {
    int g = r >> 10, j = r & 1023;
    return ((j >> 4) << 6) + (g << 4) + (j & 15);
}

// ---------- fused f32 -> bf16 pack ----------
#define T0 262144    // x    [4096,512]  -> xb flat
#define T1 786432    // h0   [4096,1024] -> hb0 flat
#define T2 1048576   // wih  [4096,512]  -> wcat interleaved rows, col off 0
#define T3 1572864   // whh  [4096,1024] -> wcat interleaved rows, col off 512
#define T4 1703936   // w1   [1024,1024] -> w116 flat
#define T5 1835008   // w2   [1024,1024] -> w216 flat
__device__ __forceinline__ u16x8 cvt8(const float* __restrict__ in, long i) {
    float4 a = *(const float4*)(in + i);
    float4 b = *(const float4*)(in + i + 4);
    u16x8 o;
    o[0] = f2bs(a.x); o[1] = f2bs(a.y); o[2] = f2bs(a.z); o[3] = f2bs(a.w);
    o[4] = f2bs(b.x); o[5] = f2bs(b.y); o[6] = f2bs(b.z); o[7] = f2bs(b.w);
    return o;
}
__global__ __launch_bounds__(256) void pack_all(const float* __restrict__ x,
                                                const float* __restrict__ h0,
                                                const float* __restrict__ wih,
                                                const float* __restrict__ whh,
                                                const float* __restrict__ w1,
                                                const float* __restrict__ w2,
                                                unsigned short* __restrict__ xb,
                                                unsigned short* __restrict__ hb0,
                                                unsigned short* __restrict__ wcat,
                                                unsigned short* __restrict__ w116,
                                                unsigned short* __restrict__ w216) {
    long g = (long)blockIdx.x * 256 + threadIdx.x;
    if (g < T0) {
        long i = g * 8;
        *(u16x8*)(xb + i) = cvt8(x, i);
    } else if (g < T1) {
        long i = (g - T0) * 8;
        *(u16x8*)(hb0 + i) = cvt8(h0, i);
    } else if (g < T2) {
        long i = (g - T1) * 8;
        int r = (int)(i / IN_DIM), c = (int)(i % IN_DIM);
        *(u16x8*)(wcat + (size_t)gperm(r) * KCAT + c) = cvt8(wih, i);
    } else if (g < T3) {
        long i = (g - T2) * 8;
        int r = (int)(i / H_DIM), c = (int)(i % H_DIM);
        *(u16x8*)(wcat + (size_t)gperm(r) * KCAT + IN_DIM + c) = cvt8(whh, i);
    } else if (g < T4) {
        long i = (g - T3) * 8;
        *(u16x8*)(w116 + i) = cvt8(w1, i);
    } else if (g < T5) {
        long i = (g - T4) * 8;
        *(u16x8*)(w216 + i) = cvt8(w2, i);
    }
}

// ---------- W2 transpose pack ----------
__global__ __launch_bounds__(256) void transp_w2(const float* __restrict__ w2,
                                                 unsigned short* __restrict__ w2t) {
    int tid = blockIdx.x * 256 + threadIdx.x;
    int t = tid & 1023;
    int jb = tid >> 10;
    float4 a = *(const float4*)(w2 + (size_t)t * H_DIM + jb * 8);
    float4 b = *(const float4*)(w2 + (size_t)t * H_DIM + jb * 8 + 4);
    float v[8] = {a.x, a.y, a.z, a.w, b.x, b.y, b.z, b.w};
    #pragma unroll
    for (int q = 0; q < 8; ++q)
        w2t[(size_t)(jb * 8 + q) * H_DIM + t] = f2bs(v[q]);
}

// ---------- bc[n] = sum_k b2[k] * W1[n,k] ----------
__global__ __launch_bounds__(256) void bck(const float* __restrict__ b2,
                                           const float* __restrict__ w1,
                                           float* __restrict__ bc) {
    __shared__ float ws[4];
    int n = blockIdx.x;
    int t = threadIdx.x;
    float4 bv = *(const float4*)(b2 + t * 4);
    float4 wv = *(const float4*)(w1 + (size_t)n * H_DIM + t * 4);
    float p = bv.x * wv.x + bv.y * wv.y + bv.z * wv.z + bv.w * wv.w;
    #pragma unroll
    for (int off = 32; off > 0; off >>= 1) p += __shfl_down(p, off);
    if ((t & 63) == 0) ws[t >> 6] = p;
    __syncthreads();
    if (t == 0) bc[n] = ws[0] + ws[1] + ws[2] + ws[3];
}

// ---------- bias sum (gate-permuted) + dt ----------
__global__ __launch_bounds__(256) void prep_small(const float* __restrict__ bih,
                                                  const float* __restrict__ bhh,
                                                  const float* __restrict__ ts,
                                                  float* __restrict__ bsum,
                                                  float* __restrict__ dtv,
                                                  int n4h, int nb) {
    int i = blockIdx.x * blockDim.x + threadIdx.x;
    if (i < n4h) bsum[gperm(i)] = bih[i] + bhh[i];
    if (i < nb)  dtv[i] = ts[2 * i + 1] - ts[2 * i];
}

// ===== 8-wave gates kernel: 128x256 tile, 512 blocks (2/CU), 3-buf, 1 barrier/K-tile =====
// MODE 0 (GX):   A = xb [B,512],  K=512;  epilogue: Gx4[m][j][0..3] = bf16(acc+bias) (u16x4 store)
// MODE 1 (CELL): A = hb [B,1024], K=1024; epilogue: fused LSTM on acc + Gx4 (u16x4 load)
// Race proof (r11): stage(kt+2) overwrites buf[(kt-1)%3], consumed before barrier(kt).
template <int MODE>
__global__ __launch_bounds__(512) void gemm8(
    const unsigned short* __restrict__ A,    // xb (MODE0) or hb (MODE1)
    const unsigned short* __restrict__ W,    // wcat (+IN_DIM for MODE1), stride KCAT
    const float* __restrict__ bias,          // MODE0: bsum (gate-permuted)
    unsigned short* __restrict__ gx,         // [B][H][4] u16 gate-last
    unsigned short* __restrict__ h_out,      // MODE1: [B,H] bf16
    float* __restrict__ c_out,               // MODE1: [B,H] f32
    const float* __restrict__ c_in) {        // MODE1: [B,H] f32
    constexpr int KA = (MODE == 0) ? IN_DIM : H_DIM;
    constexpr int NT = KA / 32;              // 16 or 32
    __shared__ unsigned short lA[3][128 * 32];   // 24 KiB
    __shared__ unsigned short lB[3][256 * 32];   // 48 KiB
    const int t = threadIdx.x;
    const int lane = t & 63;
    const int wave = t >> 6;
    const int wm = (wave >> 2) * 64;    // 0 or 64
    const int wn = (wave & 3) * 64;     // 0,64,128,192
    const int fr = lane & 15;
    const int kb = lane >> 4;
    const int tile_m = blockIdx.y * 128;
    const int tile_n = blockIdx.x * 256;

    f32x4 acc[4][4];
    #pragma unroll
    for (int i = 0; i < 4; ++i)
        #pragma unroll
        for (int j = 0; j < 4; ++j)
            acc[i][j] = (f32x4){0.f, 0.f, 0.f, 0.f};

    // loop-invariant LDS fragment byte offsets (swizzle depends only on row)
    int aoff[4], boff[4];
    #pragma unroll
    for (int i = 0; i < 4; ++i) {
        int arow = wm + i * 16 + fr;
        aoff[i] = arow * 32 + (kb ^ ((arow >> 1) & 3)) * 8;
    }
    #pragma unroll
    for (int j = 0; j < 4; ++j) {
        int brow = wn + j * 16 + fr;
        boff[j] = brow * 32 + (kb ^ ((brow >> 1) & 3)) * 8;
    }

    auto stageA = [&](int kt) {
        const int buf = kt % 3;
        int row = t >> 2;
        int g = t & 3;
        int gs = g ^ ((row >> 1) & 3);
        int kk = kt * 32 + gs * 8;
        __builtin_amdgcn_global_load_lds(
            (__attribute__((address_space(1))) void*)(A + (size_t)(tile_m + row) * KA + kk),
            (__attribute__((address_space(3))) void*)(&lA[buf][row * 32 + g * 8]), 16, 0, 0);
    };
    auto stageB = [&](int kt) {
        const int buf = kt % 3;
        #pragma unroll
        for (int j = 0; j < 2; ++j) {
            int idx = j * 512 + t;
            int row = idx >> 2;
            int g = idx & 3;
            int gs = g ^ ((row >> 1) & 3);
            int kk = kt * 32 + gs * 8;
            __builtin_amdgcn_global_load_lds(
                (__attribute__((address_space(1))) void*)(W + (size_t)(tile_n + row) * KCAT + kk),
                (__attribute__((address_space(3))) void*)(&lB[buf][row * 32 + g * 8]), 16, 0, 0);
        }
    };

    stageA(0); stageB(0);
    stageA(1); stageB(1);

    for (int kt = 0; kt < NT; ++kt) {
        const int buf = kt % 3;
        if (kt + 1 < NT) asm volatile("s_waitcnt vmcnt(3)" ::: "memory");
        else             asm volatile("s_waitcnt vmcnt(0)" ::: "memory");
        __builtin_amdgcn_s_barrier();
        asm volatile("" ::: "memory");     // nothing crosses above the barrier
        short8 bfr[4], af[4];
        #pragma unroll
        for (int j = 0; j < 4; ++j) bfr[j] = *(const short8*)&lB[buf][boff[j]];
        #pragma unroll
        for (int i = 0; i < 4; ++i) af[i] = *(const short8*)&lA[buf][aoff[i]];
        __builtin_amdgcn_s_setprio(1);
        #pragma unroll
        for (int i = 0; i < 4; ++i)
            #pragma unroll
            for (int j = 0; j < 4; ++j)
                acc[i][j] = __builtin_amdgcn_mfma_f32_16x16x32_bf16(af[i], bfr[j], acc[i][j], 0, 0, 0);
        __builtin_amdgcn_s_setprio(0);
        if (kt + 2 < NT) { stageA(kt + 2); stageB(kt + 2); }
        asm volatile("" ::: "memory");
    }

    const int jbase = ((tile_n + wn) >> 6) << 4;
    if (MODE == 0) {
        float bv[4];
        #pragma unroll
        for (int g = 0; g < 4; ++g) bv[g] = bias[tile_n + wn + g * 16 + fr];
        #pragma unroll
        for (int i = 0; i < 4; ++i) {
            #pragma unroll
            for (int r = 0; r < 4; ++r) {
                const int m = tile_m + wm + i * 16 + kb * 4 + r;
                const int j = jbase + fr;
                u16x4 o;
                #pragma unroll
                for (int g = 0; g < 4; ++g) o[g] = f2bs(acc[i][g][r] + bv[g]);
                *(u16x4*)(gx + ((size_t)m * H_DIM + j) * 4) = o;
            }
        }
    } else {
        #pragma unroll
        for (int i = 0; i < 4; ++i) {
            #pragma unroll
            for (int r = 0; r < 4; ++r) {
                const int m = tile_m + wm + i * 16 + kb * 4 + r;
                const int j = jbase + fr;
                u16x4 gv = *(const u16x4*)(gx + ((size_t)m * H_DIM + j) * 4);
                float ig = sigm(acc[i][0][r] + bs2f(gv[0]));
                float fg = sigm(acc[i][1][r] + bs2f(gv[1]));
                float gg = ftanh(acc[i][2][r] + bs2f(gv[2]));
                float og = sigm(acc[i][3][r] + bs2f(gv[3]));
                float cin = c_in[(size_t)m * H_DIM + j];
                float cn = fg * cin + ig * gg;
                float hn = og * ftanh(cn);
                h_out[(size_t)m * H_DIM + j] = f2bs(hn);
                c_out[(size_t)m * H_DIM + j] = cn;
            }
        }
    }
}

// ---------- RK4 GEMM (r13): 64x64 tile, BK=64, 2-buffer, 1 barrier/K-step ----------
// Composed z-space RK4: z_{i+1} = z1 + c_i*dt*(u_i@Wc^T + bc), Wc = W1@W2.
// EPI: 0 = bf16(v [+bias]) -> outb                      (Wc build)
//      5 = z1-GEMM: outf=z1f=v(+b1); outb=bf16(tanh(v)) (u1)
//      6 = g-GEMM; 7 = final
template <int EPI>
__global__ __launch_bounds__(256) void gemm2(
    const unsigned short* __restrict__ A1,
    const unsigned short* __restrict__ W,
    const int M, const int N, const int K,
    const float* __restrict__ bias,
    unsigned short* __restrict__ outb,
    float* __restrict__ outf,
    const float* __restrict__ z1f,
    float* __restrict__ Uf,
    const unsigned short* __restrict__ hmat,
    const float* __restrict__ dtv,
    const float alpha, const float cw, const int first, const int last) {
    constexpr int BM = 64, BN = 64, BK = 64;
    constexpr int MR = 2, NR = 2;
    __shared__ unsigned short lA[2][BM * BK];
    __shared__ unsigned short lB[2][BN * BK];
    const int t = threadIdx.x;
    const int lane = t & 63;
    const int wave = t >> 6;
    const int wm = (wave >> 1) * 32;
    const int wn = (wave & 1) * 32;
    const int fr = lane & 15;
    const int kb = lane >> 4;
    const int tile_m = blockIdx.y * BM;
    const int tile_n = blockIdx.x * BN;

    f32x4 acc[MR][NR];
    #pragma unroll
    for (int i = 0; i < MR; ++i)
        #pragma unroll
        for (int j = 0; j < NR; ++j)
            acc[i][j] = (f32x4){0.f, 0.f, 0.f, 0.f};

    const unsigned short* aptr1 = A1 + (size_t)tile_m * K;
    const unsigned short* wptr  = W + (size_t)tile_n * K;

    auto stage = [&](int kt) {
        const int buf = kt & 1;
        const int k0 = kt * BK;
        #pragma unroll
        for (int j = 0; j < 2; ++j) {
            int idx = j * 256 + t;
            int row = idx >> 3;
            int g = idx & 7;
            int col = (g ^ (row & 7)) * 8;
            __builtin_amdgcn_global_load_lds(
                (__attribute__((address_space(1))) void*)(aptr1 + (size_t)row * K + k0 + col),
                (__attribute__((address_space(3))) void*)(&lA[buf][row * BK + g * 8]), 16, 0, 0);
        }
        #pragma unroll
        for (int j = 0; j < 2; ++j) {
            int idx = j * 256 + t;
            int row = idx >> 3;
            int g = idx & 7;
            int col = (g ^ (row & 7)) * 8;
            __builtin_amdgcn_global_load_lds(
                (__attribute__((address_space(1))) void*)(wptr + (size_t)row * K + k0 + col),
                (__attribute__((address_space(3))) void*)(&lB[buf][row * BK + g * 8]), 16, 0, 0);
        }
    };

    const int NT = K / BK;   // 16
    stage(0);
    for (int kt = 0; kt < NT; ++kt) {
        const int buf = kt & 1;
        asm volatile("s_waitcnt vmcnt(0)" ::: "memory");
        __builtin_amdgcn_s_barrier();
        asm volatile("" ::: "memory");     // nothing crosses above the barrier
        short8 af[2][MR], bfr[2][NR];
        #pragma unroll
        for (int h = 0; h < 2; ++h) {
            #pragma unroll
            for (int i = 0; i < MR; ++i) {
                int arow = wm + i * 16 + fr;
                int gidx = h * 4 + kb;
                af[h][i] = *(const short8*)&lA[buf][arow * BK + (gidx ^ (arow & 7)) * 8];
            }
            #pragma unroll
            for (int j = 0; j < NR; ++j) {
                int brow = wn + j * 16 + fr;
                int gidx = h * 4 + kb;
                bfr[h][j] = *(const short8*)&lB[buf][brow * BK + (gidx ^ (brow & 7)) * 8];
            }
        }
        if (kt + 1 < NT) stage(kt + 1);    // issue next-tile loads; overlap MFMA
        #pragma unroll
        for (int h = 0; h < 2; ++h)
            #pragma unroll
            for (int i = 0; i < MR; ++i)
                #pragma unroll
                for (int j = 0; j < NR; ++j)
                    acc[i][j] = __builtin_amdgcn_mfma_f32_16x16x32_bf16(af[h][i], bfr[h][j], acc[i][j], 0, 0, 0);
        asm volatile("" ::: "memory");
    }

    #pragma unroll
    for (int i = 0; i < MR; ++i) {
        #pragma unroll
        for (int r = 0; r < 4; ++r) {
            const int m = tile_m + wm + i * 16 + kb * 4 + r;
            float dt = 0.f;
            if (EPI >= 6) dt = dtv[m];
            #pragma unroll
            for (int j = 0; j < NR; ++j) {
                const int n = tile_n + wn + j * 16 + fr;
                const size_t off = (size_t)m * N + n;
                float v = acc[i][j][r];
                if (EPI == 0) {
                    if (bias) v += bias[n];
                    outb[off] = f2bs(v);
                } else if (EPI == 5) {
                    v += bias[n];
                    outf[off] = v;                 // z1 (f32)
                    outb[off] = f2bs(ftanh(v));    // u1
                } else if (EPI == 6) {
                    v += bias[n];                  // + bc
                    float z1v = z1f[off];
                    float z = z1v + alpha * dt * v;
                    float u = ftanh(z);
                    if (first) {
                        Uf[off] = ftanh(z1v) + cw * u;
                        outb[off] = f2bs(u);
                    } else if (last) {
                        outb[off] = f2bs(Uf[off] + cw * u);
                    } else {
                        Uf[off] = Uf[off] + cw * u;
                        outb[off] = f2bs(u);
                    }
                } else { // EPI == 7: final
                    float hv = bs2f(hmat[off]);
                    outf[off] = hv + dt * (v * (1.0f / 6.0f) + bias[n]);
                }
            }
        }
    }
}

// ---------- launch ----------
extern "C" void kernel_launch(void* const* d_in, const int* in_sizes, int n_in,
                              void* d_out, int out_size, void* d_ws, size_t ws_size,
                              hipStream_t stream) {
    int IX = 0, IH0 = 1, IC0 = 2, ITS = 3, IWIH = 4, IWHH = 5, IBIH = 6, IBHH = 7,
        IW1 = 8, IB1 = 9, IW2 = 10, IB2 = 11;
    const bool sorted_ok = n_in >= 12 &&
        in_sizes[0] == 1024 && in_sizes[1] == 1024 && in_sizes[2] == 4096 &&
        in_sizes[3] == 4096 && in_sizes[4] == 4194304 && in_sizes[5] == 4194304 &&
        in_sizes[6] == 2097152 && in_sizes[7] == 8192 && in_sizes[8] == 1048576 &&
        in_sizes[9] == 1048576 && in_sizes[10] == 4194304 && in_sizes[11] == 2097152;
    if (sorted_ok) { // b1,b2,b_hh,b_ih,c0,h0,inputs,ts,w1,w2,w_hh,w_ih
        IB1 = 0; IB2 = 1; IBHH = 2; IBIH = 3; IC0 = 4; IH0 = 5;
        IX = 6; ITS = 7; IW1 = 8; IW2 = 9; IWHH = 10; IWIH = 11;
    }
    const float* x_f   = (const float*)d_in[IX];
    const float* h0_f  = (const float*)d_in[IH0];
    const float* c0_f  = (const float*)d_in[IC0];
    const float* ts_f  = (const float*)d_in[ITS];
    const float* wih_f = (const float*)d_in[IWIH];
    const float* whh_f = (const float*)d_in[IWHH];
    const float* bih_f = (const float*)d_in[IBIH];
    const float* bhh_f = (const float*)d_in[IBHH];
    const float* w1_f  = (const float*)d_in[IW1];
    const float* b1_f  = (const float*)d_in[IB1];
    const float* w2_f  = (const float*)d_in[IW2];
    const float* b2_f  = (const float*)d_in[IB2];

    constexpr size_t SZ_BIN  = (size_t)B_DIM * IN_DIM;       // 2M
    constexpr size_t SZ_BH   = (size_t)B_DIM * H_DIM;        // 4M
    constexpr size_t SZ_HH   = (size_t)H_DIM * H_DIM;        // 1M
    constexpr size_t SZ_WCAT = (size_t)4 * H_DIM * KCAT;     // 6M

    // workspace (~128 MB): f32 regions first, then bf16
    float* bsum = (float*)d_ws;                    // 4H (gate-permuted)
    float* dtv  = bsum + 4 * H_DIM;                // B
    float* bc   = dtv + B_DIM;                     // H
    float* S    = bc + H_DIM;                      // [B,H] f32: c1 then z1
    float* c1f  = S + SZ_BH;                       // [B,H] f32: Uf
    unsigned short* wcat = (unsigned short*)(c1f + SZ_BH);   // [4H,KCAT]
    unsigned short* w116 = wcat + SZ_WCAT;         // [H,H]
    unsigned short* w216 = w116 + SZ_HH;           // [H,H]
    unsigned short* w2t  = w216 + SZ_HH;           // [H,H] W2^T
    unsigned short* wc16 = w2t + SZ_HH;            // [H,H] Wc = W1@W2
    unsigned short* xb   = wc16 + SZ_HH;           // [B,512]
    unsigned short* hb0  = xb + SZ_BIN;            // [B,H]
    unsigned short* hb1  = hb0 + SZ_BH;            // [B,H]
    unsigned short* hb2  = hb1 + SZ_BH;            // [B,H]
    unsigned short* ubuf = hb2 + SZ_BH;            // [B,H]
    unsigned short* ybuf = ubuf + SZ_BH;           // [B,H]
    unsigned short* Gx   = ybuf + SZ_BH;           // [B][H][4] u16 gate-last (32 MB)

    float* out_ht = (float*)d_out;                 // [B,H] f32
    float* out_c  = out_ht + SZ_BH;                // [B,H] f32
    float* z1f = S;                                // z1 reuses S (c1 consumed by cell2 first)
    float* Uf  = c1f;

    const int TB = 256;
    pack_all<<<T5 / TB, TB, 0, stream>>>(x_f, h0_f, wih_f, whh_f, w1_f, w2_f,
                                         xb, hb0, wcat, w116, w216);
    transp_w2<<<(H_DIM * H_DIM / 8) / TB, TB, 0, stream>>>(w2_f, w2t);
    prep_small<<<(4 * H_DIM) / TB, TB, 0, stream>>>(bih_f, bhh_f, ts_f, bsum, dtv, 4 * H_DIM, B_DIM);
    bck<<<H_DIM, TB, 0, stream>>>(b2_f, w1_f, bc);

    dim3 g8(4 * H_DIM / 256, B_DIM / 128);     // (16,32) = 512 blocks, 512 thr, 2/CU
    dim3 gSm(H_DIM / 64, B_DIM / 64);          // (16,64) = 1024 blocks
    dim3 gWc(H_DIM / 64, H_DIM / 64);          // (16,16) = 256 blocks

    // Wc = W1 @ W2
    gemm2<0><<<gWc, TB, 0, stream>>>(w116, w2t, H_DIM, H_DIM, H_DIM, nullptr,
                                     wc16, nullptr, nullptr, nullptr, nullptr, nullptr, 0.f, 0.f, 0, 0);

    // Gx = x @ Wih^T + bsum  (K=512, computed ONCE for both cells; gate-last u16x4)
    gemm8<0><<<g8, 512, 0, stream>>>(xb, wcat, bsum, Gx, nullptr, nullptr, nullptr);

    // cell 1 (K=1024 h-part + Gx in epilogue): h0 -> h1 (hb1), c1 -> S
    gemm8<1><<<g8, 512, 0, stream>>>(hb0, wcat + IN_DIM, nullptr, Gx, hb1, S, c0_f);
    // cell 2: h1 -> h2 (hb2), c2 -> out_c
    gemm8<1><<<g8, 512, 0, stream>>>(hb1, wcat + IN_DIM, nullptr, Gx, hb2, out_c, S);

    // Composed RK4 in z-space:
    gemm2<5><<<gSm, TB, 0, stream>>>(hb2, w116, B_DIM, H_DIM, H_DIM, b1_f,
                                     ubuf, z1f, nullptr, nullptr, nullptr, nullptr, 0.f, 0.f, 0, 0);
    gemm2<6><<<gSm, TB, 0, stream>>>(ubuf, wc16, B_DIM, H_DIM, H_DIM, bc,
                                     ybuf, nullptr, z1f, Uf, nullptr, dtv, 0.5f, 2.0f, 1, 0);
    gemm2<6><<<gSm, TB, 0, stream>>>(ybuf, wc16, B_DIM, H_DIM, H_DIM, bc,
                                     ubuf, nullptr, z1f, Uf, nullptr, dtv, 0.5f, 2.0f, 0, 0);
    gemm2<6><<<gSm, TB, 0, stream>>>(ubuf, wc16, B_DIM, H_DIM, H_DIM, bc,
                                     hb1, nullptr, z1f, Uf, nullptr, dtv, 1.0f, 1.0f, 0, 1);
    gemm2<7><<<gSm, TB, 0, stream>>>(hb1, w216, B_DIM, H_DIM, H_DIM, b2_f,
                                     nullptr, out_ht, nullptr, nullptr, hb2, dtv, 0.f, 0.f, 0, 0);
}